// Round 10
// baseline (2411.445 us; speedup 1.0000x reference)
//
#include <hip/hip_runtime.h>
#include <hip/hip_bf16.h>

typedef unsigned short ushort_t;
typedef unsigned int u32;
typedef _Float16 f16;
typedef __attribute__((ext_vector_type(8))) short short8;
typedef __attribute__((ext_vector_type(4))) float f32x4;
typedef __attribute__((ext_vector_type(8))) _Float16 f16x8;
typedef __attribute__((ext_vector_type(4))) unsigned int u32x4;

#define T_ 64
#define B_ 16
#define S_ 400
#define E_ 128
#define H_ 256
#define H2_ 512
#define DV_ 50000
#define VOC_ 50050
#define CAT_ 896
#define NCLUS 8
#define RSL 50

// ---- d_out float offsets
#define YP_SZ   ((size_t)T_*B_*VOC_)              // 51,251,200 floats
#define HS_OFF  (YP_SZ)
#define WW_OFF  (HS_OFF + (size_t)T_*B_*H_)
#define CV_OFF  (WW_OFF + (size_t)T_*B_*S_)
// scratch carved out of the y_pred region (all consumed before gemm2 overwrites it):
#define ENCP16_OFF ((size_t)0)         // f16[16][400][512]
#define ENC16_OFF  ((size_t)1638400)   // f16[16][400][512]
#define WS16_OFF   ((size_t)3276800)   // f16[512][256]
#define W216_OFF   ((size_t)3342336)   // f16[768][512]
#define CTXALL_OFF ((size_t)3538944)   // f32[1024][512]
#define GX1_OFF    ((size_t)4063232)   // f32[1024][768]
#define WH216_OFF  ((size_t)4947968)   // f16[768][256]
#define WH116T_OFF ((size_t)5046272)   // f16[8][768][32] col-panel pack of Whh1
// tag-stamped exchange slots (dead y_pred region):
#define SYNC_OFF   ((size_t)5144576)
#define S1STR      528                  // payload[0..511]=uctx, [512]=esum, tag@520
#define S1TAG      520
#define S2STR      816                  // payload[0..767]=gh1p, [768..799]=s2, tag@808
#define S2TAG      808
#define S2REG      ((size_t)16*NCLUS*S1STR)
#define SYNC_FLOATS ((size_t)16*NCLUS*(S1STR + S2STR))
#define WH16F_OFF  ((size_t)5316608)   // f16[512][512]  (Wh converted)
#define V1HF_OFF   ((size_t)5447680)   // f16[256][896]  (V1w converted)

// ---- ws float offsets
#define WS_ROWSUM 0      // f32[1024]
#define WS_GV     1024   // f32[1024]
#define WS_G1     2048   // bf16[1024][256]

__device__ __forceinline__ float fsig(float x){ return 1.f/(1.f+__expf(-x)); }
__device__ __forceinline__ float ftanh(float x){ float e=__expf(2.f*x); return 1.f - 2.f/(e+1.f); }

#define PADK(k) ((k) + (((k)>>5)<<2))

#define AT_ST(p, v)  __hip_atomic_store((p), (v), __ATOMIC_RELAXED, __HIP_MEMORY_SCOPE_AGENT)
#define AT_LD(p)     __hip_atomic_load((p), __ATOMIC_RELAXED, __HIP_MEMORY_SCOPE_AGENT)
#define AT_STI(p, v) __hip_atomic_store((int*)(p), (v), __ATOMIC_RELAXED, __HIP_MEMORY_SCOPE_AGENT)
#define AT_LDI(p)    __hip_atomic_load((const int*)(p), __ATOMIC_RELAXED, __HIP_MEMORY_SCOPE_AGENT)

// ---- dynamic smem byte offsets (scan)
#define SM_ENC    0
#define SM_ENCP   51200
#define SM_GH1    102400
#define SM_SWS    105472
#define SM_VP     107776
#define SM_WCP    110080
#define SM_S1     115456
#define SM_G2H    116864
#define SM_COV    117248
#define SM_EV     117504
#define SM_XM     117760
#define SM_YM     118016
#define SM_S1H    118784
#define SM_CTXH   119296
#define SM_S2S    120320
#define SM_B1     120512
#define SM_B2     123584
#define SM_B3     126656
#define SM_GX     129728
#define SM_BYTES  132800

// ---------------------------------------------------------------- small converts
__global__ __launch_bounds__(256)
void cvt16_kernel(const float* src, f16* dst, int n){
  int i = blockIdx.x*256 + threadIdx.x;
  if (i < n) dst[i] = (f16)src[i];
}

__global__ __launch_bounds__(256)
void repack_kernel(const float* enc, f16* enc16){
  int s = blockIdx.x, b = blockIdx.y;
  const float* src = enc + ((size_t)s*B_ + b)*H2_;
  f16* dst = enc16 + ((size_t)b*S_ + s)*H2_;
  for (int k = threadIdx.x; k < H2_; k += 256) dst[k] = (f16)src[k];
}

// Whh1 [768][256] -> panels [jj][768][32]
__global__ __launch_bounds__(256)
void packWhh1_kernel(const float* W, f16* dst){
  int r = blockIdx.x, c = threadIdx.x;
  int jq = c >> 5, cc = c & 31;
  dst[((size_t)jq*768 + r)*32 + cc] = (f16)W[(size_t)r*H_ + c];
}

// ---------------------------------------------------------------- gx1 = emb @ Wih1^T + bih1
__global__ __launch_bounds__(256)
void gx1_kernel(const float* emb, const float* Wih1, const float* bih1, float* dout){
  __shared__ float As[64][33];
  __shared__ float Bs[128][33];
  int m0 = blockIdx.x*64, n0 = blockIdx.y*128;
  int tx = threadIdx.x & 15, ty = threadIdx.x >> 4;
  float acc[4][8] = {};
  for (int kt = 0; kt < E_; kt += 32){
    for (int l = threadIdx.x; l < 64*32; l += 256){
      int m = l>>5, k = l&31; As[m][k] = emb[(size_t)(m0+m)*E_ + kt + k];
    }
    for (int l = threadIdx.x; l < 128*32; l += 256){
      int n = l>>5, k = l&31; Bs[n][k] = Wih1[(size_t)(n0+n)*E_ + kt + k];
    }
    __syncthreads();
    for (int k = 0; k < 32; ++k){
      float a[4], bv[8];
      #pragma unroll
      for (int i=0;i<4;++i) a[i] = As[ty+16*i][k];
      #pragma unroll
      for (int j=0;j<8;++j) bv[j] = Bs[tx+16*j][k];
      #pragma unroll
      for (int i=0;i<4;++i)
        #pragma unroll
        for (int j=0;j<8;++j) acc[i][j] += a[i]*bv[j];
    }
    __syncthreads();
  }
  #pragma unroll
  for (int i=0;i<4;++i)
    #pragma unroll
    for (int j=0;j<8;++j){
      int m = m0 + ty + 16*i, n = n0 + tx + 16*j;
      dout[GX1_OFF + (size_t)m*768 + n] = acc[i][j] + bih1[n];
    }
}

// ---------------------------------------------------------------- enc_proj via f16 MFMA -> encp16
__global__ __launch_bounds__(256)
void encproj_mfma(const f16* enc16, const f16* Wh16, const float* battn, f16* ep16){
  int nx = blockIdx.x, my = blockIdx.y, bz = blockIdx.z;
  int tid = threadIdx.x;
  int w = tid >> 6, lane = tid & 63;
  int c16 = lane & 15, kg = lane >> 4;
  int m0 = my*64, n0 = nx*128 + w*32;
  f32x4 acc[4][2] = {};
  int col0 = n0 + c16, col1 = n0 + 16 + c16;
  for (int ks = 0; ks < 16; ++ks){
    int k0 = ks*32 + kg*8;
    f16x8 b0 = *(const f16x8*)(Wh16 + (size_t)col0*H2_ + k0);
    f16x8 b1 = *(const f16x8*)(Wh16 + (size_t)col1*H2_ + k0);
    #pragma unroll
    for (int mf = 0; mf < 4; ++mf){
      int s = m0 + mf*16 + c16; if (s > S_-1) s = S_-1;
      f16x8 a = *(const f16x8*)(enc16 + ((size_t)bz*S_ + s)*H2_ + k0);
      acc[mf][0] = __builtin_amdgcn_mfma_f32_16x16x32_f16(a, b0, acc[mf][0], 0, 0, 0);
      acc[mf][1] = __builtin_amdgcn_mfma_f32_16x16x32_f16(a, b1, acc[mf][1], 0, 0, 0);
    }
  }
  #pragma unroll
  for (int mf = 0; mf < 4; ++mf)
    #pragma unroll
    for (int nf = 0; nf < 2; ++nf){
      int col = n0 + nf*16 + c16;
      float bb = battn[col];
      #pragma unroll
      for (int r = 0; r < 4; ++r){
        int s = m0 + mf*16 + kg*4 + r;
        if (s < S_) ep16[((size_t)bz*S_ + s)*H2_ + col] = (f16)(acc[mf][nf][r] + bb);
      }
    }
}

// ---------------------------------------------------------------- f16 GEMV (1024 threads, 128 octets)
template<int R, int K, bool PAD>
__device__ __forceinline__ void gemv_f16t(const f16* W, const f16* xh, float* out_l, int tid){
  int o = tid >> 3, l8 = tid & 7;
  constexpr int NI = K/64;
  const f16x8* x8 = (const f16x8*)xh;
  f16x8 xv[NI];
  #pragma unroll
  for (int i = 0; i < NI; ++i) xv[i] = x8[i*8 + l8];
  #pragma unroll
  for (int it = 0; it < R/128; ++it){
    int d = o + it*128;
    const f16x8* w8 = (const f16x8*)(W + (size_t)d*K);
    float acc = 0.f;
    #pragma unroll
    for (int i = 0; i < NI; ++i){
      f16x8 w = w8[i*8 + l8];
      #pragma unroll
      for (int e = 0; e < 8; ++e) acc += (float)w[e] * (float)xv[i][e];
    }
    acc += __shfl_xor(acc,1,8); acc += __shfl_xor(acc,2,8); acc += __shfl_xor(acc,4,8);
    if (l8 == 0) out_l[PAD ? PADK(d) : d] = acc;
  }
}

// spin until all 8 tags of this cluster's region equal `want`
__device__ __forceinline__ void spin_tags(const float* base, int stride, int tagoff, int want, int tid){
  if (tid < 64){
    bool mine = tid < NCLUS;
    const float* tp = base + (size_t)(mine ? tid : 0)*stride + tagoff;
    while (true){
      int v = mine ? AT_LDI(tp) : want;
      if (__all(v == want)) break;
      __builtin_amdgcn_s_sleep(1);
    }
  }
  __syncthreads();
}

// ---------------------------------------------------------------- persistent scan: 128 blocks (8 per b, same-XCD clusters)
__global__ __launch_bounds__(1024)
void scan_kernel(const float* xm, const float* ym,
                 const float* bhh1, const float* bih2, const float* bhh2,
                 const float* Wc, const float* Vat,
                 const float* inith, const float* initc,
                 float* dout)
{
  extern __shared__ char smem[];
  f16*   enc_s  = (f16*)(smem + SM_ENC);
  f16*   encp_s = (f16*)(smem + SM_ENCP);
  float* sWs_p  = (float*)(smem + SM_SWS);
  float* Vp     = (float*)(smem + SM_VP);
  float* Wcp    = (float*)(smem + SM_WCP);
  float* s1_l   = (float*)(smem + SM_S1);
  float* g2h_l  = (float*)(smem + SM_G2H);
  float* cov_l  = (float*)(smem + SM_COV);
  float* ev_l   = (float*)(smem + SM_EV);
  float* xm_l   = (float*)(smem + SM_XM);
  float* ym_l   = (float*)(smem + SM_YM);
  f16*   s1h    = (f16*)(smem + SM_S1H);
  f16*   ctxh   = (f16*)(smem + SM_CTXH);
  float* s2s    = (float*)(smem + SM_S2S);
  float* b1l    = (float*)(smem + SM_B1);
  float* b2l    = (float*)(smem + SM_B2);
  float* b3l    = (float*)(smem + SM_B3);
  float* gxbuf  = (float*)(smem + SM_GX);

  const f16* Ws16   = (const f16*)(dout + WS16_OFF);
  const f16* W216   = (const f16*)(dout + W216_OFF);
  const f16* Wh216  = (const f16*)(dout + WH216_OFF);
  const f16* Wh116T = (const f16*)(dout + WH116T_OFF);
  const float* gx1  = dout + GX1_OFF;

  int blk = blockIdx.x, tid = threadIdx.x;
  // same-XCD clusters: blk = jj*16 + b  ->  XCD(blk%8) == b%8 for all jj
  int b = blk & 15, jj = blk >> 4;
  int wv = tid >> 6, ln = tid & 63;

  float* sl1 = dout + SYNC_OFF + (size_t)b*NCLUS*S1STR;       // cluster region
  float* sl2 = dout + SYNC_OFF + S2REG + (size_t)b*NCLUS*S2STR;
  float* sl1my = sl1 + (size_t)jj*S1STR;
  float* sl2my = sl2 + (size_t)jj*S2STR;

  // ---- init: pin enc/encp slice in LDS, load state, seed slot2 with inith
  {
    const u32x4* encg  = (const u32x4*)(dout + ENC16_OFF)  + (size_t)b*25600 + jj*3200;
    const u32x4* encpg = (const u32x4*)(dout + ENCP16_OFF) + (size_t)b*25600 + jj*3200;
    u32x4* encs4  = (u32x4*)enc_s;
    u32x4* encps4 = (u32x4*)encp_s;
    for (int i = tid; i < 3200; i += 1024){ encs4[i] = encg[i]; encps4[i] = encpg[i]; }
  }
  if (tid < 32)  s2s[tid] = inith[b*H_ + jj*32 + tid];
  if (tid < 512){ Vp[PADK(tid)] = Vat[tid]; Wcp[PADK(tid)] = Wc[tid]; }
  if (tid < RSL){ int s = jj*RSL + tid; cov_l[tid] = initc[b*S_ + s]; xm_l[tid] = xm[(size_t)s*B_ + b]; }
  if (tid >= 512 && tid < 576) ym_l[tid-512] = ym[(tid-512)*B_ + b];
  if (tid < 768){ b1l[tid] = bhh1[tid]; b2l[tid] = bih2[tid]; b3l[tid] = bhh2[tid];
                  gxbuf[tid] = gx1[(size_t)b*768 + tid]; }
  __syncthreads();
  // A' seed: gh1 partial from inith slice
  if (tid < 768){
    const f16x8* p8 = (const f16x8*)(Wh116T + ((size_t)jj*768 + tid)*32);
    float acc = 0.f;
    #pragma unroll
    for (int c4 = 0; c4 < 4; ++c4){
      f16x8 w = p8[c4];
      #pragma unroll
      for (int e = 0; e < 8; ++e) acc += (float)w[e] * s2s[c4*8+e];
    }
    AT_ST(&sl2my[tid], acc);
  } else if (tid < 800){
    AT_ST(&sl2my[768 + (tid-768)], s2s[tid-768]);
  }
  __syncthreads();
  if (tid == 0) AT_STI(&sl2my[S2TAG], 1);

  for (int t = 0; t < T_; ++t){
    int row = t*B_ + b;
    int want = t + 1;
    // S2 spin: hidden + gh1 partials for this step available
    spin_tags(sl2, S2STR, S2TAG, want, tid);
    // B (merged with gather): thread j gathers its 3 gate partial-sums + h, computes s1
    if (tid < 256){
      int j = tid;
      float ar = 0.f, az = 0.f, an = 0.f;
      #pragma unroll
      for (int q = 0; q < NCLUS; ++q){
        const float* sq = sl2 + (size_t)q*S2STR;
        ar += AT_LD(&sq[j]); az += AT_LD(&sq[256+j]); an += AT_LD(&sq[512+j]);
      }
      float h = AT_LD(&sl2[(size_t)(j>>5)*S2STR + 768 + (j&31)]);
      float r = fsig(gxbuf[j]      + ar + b1l[j]);
      float z = fsig(gxbuf[256+j]  + az + b1l[256+j]);
      float n = ftanh(gxbuf[512+j] + r*(an + b1l[512+j]));
      float ymv = ym_l[t];
      float s1 = ymv*((1.f-z)*n + z*h) + (1.f-ymv)*h;
      s1_l[j] = s1; s1h[j] = (f16)s1;
    }
    __syncthreads();
    // C: sWs = Ws @ s1 (replicated, padded)
    gemv_f16t<512,256,true>(Ws16, s1h, sWs_p, tid);
    __syncthreads();
    // D: scores over local 50 rows (encp in LDS)
    {
      int kp = PADK(ln*8);
      float4 sA = *(const float4*)&sWs_p[kp], sB = *(const float4*)&sWs_p[kp+4];
      float4 vA = *(const float4*)&Vp[kp],    vB = *(const float4*)&Vp[kp+4];
      float4 cA = *(const float4*)&Wcp[kp],   cB = *(const float4*)&Wcp[kp+4];
      const f16x8* eps = (const f16x8*)encp_s;
      #pragma unroll
      for (int i = 0; i < 4; ++i){
        int r = wv + 16*i;
        if (r < RSL){
          f16x8 eu = eps[r*64 + ln];
          float cv = cov_l[r];
          float sc = 0.f;
          sc += ftanh((float)eu[0] + sA.x + cv*cA.x)*vA.x;
          sc += ftanh((float)eu[1] + sA.y + cv*cA.y)*vA.y;
          sc += ftanh((float)eu[2] + sA.z + cv*cA.z)*vA.z;
          sc += ftanh((float)eu[3] + sA.w + cv*cA.w)*vA.w;
          sc += ftanh((float)eu[4] + sB.x + cv*cB.x)*vB.x;
          sc += ftanh((float)eu[5] + sB.y + cv*cB.y)*vB.y;
          sc += ftanh((float)eu[6] + sB.z + cv*cB.z)*vB.z;
          sc += ftanh((float)eu[7] + sB.w + cv*cB.w)*vB.w;
          sc += __shfl_xor(sc,1);  sc += __shfl_xor(sc,2);  sc += __shfl_xor(sc,4);
          sc += __shfl_xor(sc,8);  sc += __shfl_xor(sc,16); sc += __shfl_xor(sc,32);
          if (ln == 0){
            float xmv = xm_l[r];
            ev_l[r] = __expf((xmv == 0.f) ? -1e9f : xmv*sc);  // |score|<~25: safe w/o max-sub
          }
        }
      }
    }
    __syncthreads();
    // EF: local ctx partial + esum partial -> slot1
    if (tid < 512){
      float acc = 0.f;
      #pragma unroll 5
      for (int s = 0; s < RSL; ++s) acc += ev_l[s] * (float)enc_s[s*H2_ + tid];
      AT_ST(&sl1my[tid], acc);
    } else if (tid >= 960){
      int l = tid - 960;
      float v = (l < RSL) ? ev_l[l] : 0.f;
      v += __shfl_xor(v,1);  v += __shfl_xor(v,2);  v += __shfl_xor(v,4);
      v += __shfl_xor(v,8);  v += __shfl_xor(v,16); v += __shfl_xor(v,32);
      if (l == 0) AT_ST(&sl1my[512], v);
    }
    __syncthreads();   // drain payload stores
    if (tid == 0) AT_STI(&sl1my[S1TAG], want);
    // X1 (hidden before spin): gx1[t+1] prefetch + g2h 3-gate rows per octet o<32
    float gxn = 0.f;
    if (tid < 768){
      int tn = (t+1 < T_) ? t+1 : t;
      gxn = gx1[(size_t)(tn*B_ + b)*768 + tid];
    }
    {
      int o = tid >> 3, l8 = tid & 7;
      if (o < 32){
        int j = jj*32 + o;
        const f16x8* y8 = (const f16x8*)s1h;
        f16x8 ya[4];
        #pragma unroll
        for (int i = 0; i < 4; ++i) ya[i] = y8[i*8 + l8];
        float ar = 0.f, az = 0.f, an = 0.f;
        const f16x8* wr = (const f16x8*)(Wh216 + (size_t)j*H_);
        const f16x8* wz = (const f16x8*)(Wh216 + (size_t)(256+j)*H_);
        const f16x8* wn = (const f16x8*)(Wh216 + (size_t)(512+j)*H_);
        #pragma unroll
        for (int i = 0; i < 4; ++i){
          f16x8 a = wr[i*8 + l8], c = wz[i*8 + l8], d = wn[i*8 + l8];
          #pragma unroll
          for (int e = 0; e < 8; ++e){
            float xv = (float)ya[i][e];
            ar += (float)a[e]*xv; az += (float)c[e]*xv; an += (float)d[e]*xv;
          }
        }
        ar += __shfl_xor(ar,1,8); ar += __shfl_xor(ar,2,8); ar += __shfl_xor(ar,4,8);
        az += __shfl_xor(az,1,8); az += __shfl_xor(az,2,8); az += __shfl_xor(az,4,8);
        an += __shfl_xor(an,1,8); an += __shfl_xor(an,2,8); an += __shfl_xor(an,4,8);
        if (l8 == 0){ g2h_l[o] = ar; g2h_l[32+o] = az; g2h_l[64+o] = an; }
      }
    }
    if (tid < 768) gxbuf[tid] = gxn;
    // S1 spin
    spin_tags(sl1, S1STR, S1TAG, want, tid);
    // G (merged gather+finalize): every thread sums the 8 esums itself
    {
      float es = 0.f;
      #pragma unroll
      for (int q = 0; q < NCLUS; ++q) es += AT_LD(&sl1[(size_t)q*S1STR + 512]);
      float inv = 1.f/es;
      if (tid < 512){
        float us = 0.f;
        #pragma unroll
        for (int q = 0; q < NCLUS; ++q) us += AT_LD(&sl1[(size_t)q*S1STR + tid]);
        float v = us*inv;
        ctxh[tid] = (f16)v;
        if (jj == 0) __builtin_nontemporal_store(v, &dout[CTXALL_OFF + (size_t)row*H2_ + tid]);
      } else if (tid >= 640 && tid < 640 + RSL){
        int r = tid - 640;
        float w_ = ev_l[r]*inv;
        size_t ro = (size_t)row*S_ + jj*RSL + r;
        __builtin_nontemporal_store(w_, &dout[WW_OFF + ro]);
        float co = cov_l[r];
        __builtin_nontemporal_store(co, &dout[CV_OFF + ro]);
        cov_l[r] = co + w_;
      }
    }
    __syncthreads();
    // H+I merged: octet o<32 computes 3 g2x gate rows for output j, lane0 applies gates
    {
      int o = tid >> 3, l8 = tid & 7;
      if (o < 32){
        int j = jj*32 + o;
        const f16x8* x8 = (const f16x8*)ctxh;
        f16x8 xa[8];
        #pragma unroll
        for (int i = 0; i < 8; ++i) xa[i] = x8[i*8 + l8];
        float ar = 0.f, az = 0.f, an = 0.f;
        const f16x8* wr = (const f16x8*)(W216 + (size_t)j*H2_);
        const f16x8* wz = (const f16x8*)(W216 + (size_t)(256+j)*H2_);
        const f16x8* wn = (const f16x8*)(W216 + (size_t)(512+j)*H2_);
        #pragma unroll
        for (int i = 0; i < 8; ++i){
          f16x8 a = wr[i*8 + l8], c = wz[i*8 + l8], d = wn[i*8 + l8];
          #pragma unroll
          for (int e = 0; e < 8; ++e){
            float xv = (float)xa[i][e];
            ar += (float)a[e]*xv; az += (float)c[e]*xv; an += (float)d[e]*xv;
          }
        }
        ar += __shfl_xor(ar,1,8); ar += __shfl_xor(ar,2,8); ar += __shfl_xor(ar,4,8);
        az += __shfl_xor(az,1,8); az += __shfl_xor(az,2,8); az += __shfl_xor(az,4,8);
        an += __shfl_xor(an,1,8); an += __shfl_xor(an,2,8); an += __shfl_xor(an,4,8);
        if (l8 == 0){
          float gr = fsig(ar + b2l[j]     + g2h_l[o]    + b3l[j]);
          float gz = fsig(az + b2l[256+j] + g2h_l[32+o] + b3l[256+j]);
          float gn = ftanh(an + b2l[512+j] + gr*(g2h_l[64+o] + b3l[512+j]));
          float s1v = s1_l[j];
          float ymv = ym_l[t];
          float s2 = ymv*((1.f-gz)*gn + gz*s1v) + (1.f-ymv)*s1v;
          s2s[o] = s2;
          AT_ST(&sl2my[768 + o], s2);
          __builtin_nontemporal_store(s2, &dout[HS_OFF + (size_t)row*H_ + j]);
        }
      }
    }
    __syncthreads();
    // A': gh1 partial for next step = Wh116T[jj] @ s2_slice (panel from L2)
    if (tid < 768){
      const f16x8* p8 = (const f16x8*)(Wh116T + ((size_t)jj*768 + tid)*32);
      float acc = 0.f;
      #pragma unroll
      for (int c4 = 0; c4 < 4; ++c4){
        f16x8 w = p8[c4];
        #pragma unroll
        for (int e = 0; e < 8; ++e) acc += (float)w[e] * s2s[c4*8+e];
      }
      AT_ST(&sl2my[tid], acc);
    }
    __syncthreads();   // drain payload stores
    if (tid == 0) AT_STI(&sl2my[S2TAG], t + 2);
  }
}

// ---------------------------------------------------------------- G1 = tanh([hs|ctx|emb]@V1^T+b) bf16, g = sigmoid(...Wp)
__global__ __launch_bounds__(512)
void head_kernel(const float* emb, const f16* V1H, const float* V1b,
                 const float* Wpw, const float* Wpb, float* dout, float* ws)
{
  __shared__ float hc[2][CAT_];
  int t = blockIdx.x, b0 = blockIdx.y*2, tid = threadIdx.x;
  for (int i = tid; i < 2*CAT_; i += 512){
    int bb = i / CAT_, k = i % CAT_;
    int b = b0 + bb;
    float v;
    if (k < H_)           v = dout[HS_OFF     + ((size_t)(t*B_+b))*H_  + k];
    else if (k < H_+H2_)  v = dout[CTXALL_OFF + ((size_t)(t*B_+b))*H2_ + (k-H_)];
    else                  v = emb[((size_t)(t*B_+b))*E_ + (k-H_-H2_)];
    hc[bb][k] = v;
  }
  __syncthreads();
  __hip_bfloat16* G1 = (__hip_bfloat16*)(ws + WS_G1);
  {
    int j = tid & 255, bb = tid >> 8;
    const f16x8* wv8 = (const f16x8*)(V1H + (size_t)j*CAT_);
    float acc = 0.f;
    #pragma unroll 4
    for (int kk = 0; kk < CAT_/8; ++kk){
      f16x8 w = wv8[kk];
      #pragma unroll
      for (int e = 0; e < 8; ++e) acc += hc[bb][kk*8+e]*(float)w[e];
    }
    G1[((size_t)(t*B_ + b0 + bb))*H_ + j] = __float2bfloat16(ftanh(acc + V1b[j]));
  }
  if (tid < 128){
    int bb = tid >> 6, l = tid & 63;
    float acc = 0.f;
    for (int k = l; k < CAT_; k += 64) acc += hc[bb][k]*Wpw[k];
    acc += __shfl_xor(acc,1);  acc += __shfl_xor(acc,2);  acc += __shfl_xor(acc,4);
    acc += __shfl_xor(acc,8);  acc += __shfl_xor(acc,16); acc += __shfl_xor(acc,32);
    if (l == 0) ws[WS_GV + t*B_ + b0 + bb] = fsig(acc + Wpb[0]);
  }
}

// ---------------------------------------------------------------- logits GEMM (bf16 MFMA, 256-row m-tile) + exp + rowsums
__global__ __launch_bounds__(256)
void gemm2_kernel(const ushort_t* G1, const float* V2w, const float* V2b,
                  float* dout, float* rowsum)
{
  __shared__ float rows_l[256];
  int tid = threadIdx.x;
  rows_l[tid] = 0.f;
  int m0 = blockIdx.y * 256;
  int n0 = blockIdx.x * 64;
  int lane = tid & 63, w = tid >> 6;
  int c16 = lane & 15, kg = lane >> 4;
  int col = n0 + w*16 + c16;
  int colc = col < DV_ ? col : DV_-1;
  bool valid = col < DV_;
  f32x4 acc[16] = {};
  const float* brow = V2w + (size_t)colc*H_;
  for (int ks = 0; ks < 8; ++ks){
    int k0 = ks*32 + kg*8;
    short8 bf;
    #pragma unroll
    for (int i = 0; i < 8; ++i){
      __hip_bfloat16 hb = __float2bfloat16(brow[k0+i]);
      union { __hip_bfloat16 h; short s; } u; u.h = hb;
      bf[i] = u.s;
    }
    #pragma unroll
    for (int mf = 0; mf < 16; ++mf){
      const short8* ap = (const short8*)(G1 + ((size_t)(m0 + mf*16 + c16))*H_ + k0);
      acc[mf] = __builtin_amdgcn_mfma_f32_16x16x32_bf16(*ap, bf, acc[mf], 0, 0, 0);
    }
  }
  float bias = valid ? V2b[colc] : 0.f;
  __syncthreads();
  #pragma unroll
  for (int mf = 0; mf < 16; ++mf){
    #pragma unroll
    for (int r = 0; r < 4; ++r){
      float v = valid ? __expf(acc[mf][r] + bias) : 0.f;
      int rloc = mf*16 + kg*4 + r;
      if (valid) __builtin_nontemporal_store(v, &dout[(size_t)(m0 + rloc)*VOC_ + col]);
      float s = v;
      s += __shfl_xor(s, 1, 16); s += __shfl_xor(s, 2, 16);
      s += __shfl_xor(s, 4, 16); s += __shfl_xor(s, 8, 16);
      if (c16 == 0) atomicAdd(&rows_l[rloc], s);
    }
  }
  __syncthreads();
  atomicAdd(&rowsum[m0 + tid], rows_l[tid]);
}

// ---------------------------------------------------------------- fused normalize + pointer scatter (+ EXT zero)
__global__ __launch_bounds__(256)
void normscatter_kernel(float* dout, const float* ws, const int* xidx){
  int row = blockIdx.x; int b = row & 15;
  float gv = ws[WS_GV + row];
  float sc = gv / ws[WS_ROWSUM + row];
  float g1 = 1.f - gv;
  float2* y2 = (float2*)(dout + (size_t)row * VOC_);
  for (int i = threadIdx.x; i < VOC_/2; i += 256){
    float2 v = y2[i];
    int e0 = 2*i;
    v.x = (e0   < DV_) ? v.x*sc : 0.f;
    v.y = (e0+1 < DV_) ? v.y*sc : 0.f;
    y2[i] = v;
  }
  __syncthreads();
  const float* ww = dout + WW_OFF + (size_t)row*S_;
  float* y = dout + (size_t)row*VOC_;
  for (int s = threadIdx.x; s < S_; s += 256){
    atomicAdd(&y[xidx[(size_t)s*B_ + b]], g1*ww[s]);
  }
}

extern "C" void kernel_launch(void* const* d_in, const int* in_sizes, int n_in,
                              void* d_out, int out_size, void* d_ws, size_t ws_size,
                              hipStream_t stream)
{
  (void)in_sizes; (void)n_in; (void)out_size; (void)ws_size;
  const float* emb   = (const float*)d_in[0];
  const float* enc   = (const float*)d_in[1];
  const float* inith = (const float*)d_in[2];
  const float* xmask = (const float*)d_in[3];
  const float* ymask = (const float*)d_in[4];
  const int*   xidx  = (const int*)d_in[5];
  const float* initc = (const float*)d_in[7];
  const float* Wh    = (const float*)d_in[8];
  const float* Wss   = (const float*)d_in[9];
  const float* Wc    = (const float*)d_in[10];
  const float* battn = (const float*)d_in[11];
  const float* Vat   = (const float*)d_in[12];
  const float* Wih1  = (const float*)d_in[13];
  const float* Whh1  = (const float*)d_in[14];
  const float* bih1  = (const float*)d_in[15];
  const float* bhh1  = (const float*)d_in[16];
  const float* Wih2  = (const float*)d_in[17];
  const float* Whh2  = (const float*)d_in[18];
  const float* bih2  = (const float*)d_in[19];
  const float* bhh2  = (const float*)d_in[20];
  const float* V1w   = (const float*)d_in[21];
  const float* V1b   = (const float*)d_in[22];
  const float* V2w   = (const float*)d_in[23];
  const float* V2b   = (const float*)d_in[24];
  const float* Wpw   = (const float*)d_in[25];
  const float* Wpb   = (const float*)d_in[26];
  float* out = (float*)d_out;
  float* ws  = (float*)d_ws;

  hipFuncSetAttribute(reinterpret_cast<const void*>(scan_kernel),
                      hipFuncAttributeMaxDynamicSharedMemorySize, SM_BYTES);

  hipMemsetAsync(d_ws, 0, 2048*sizeof(float), stream);                       // rowsum + gv
  hipMemsetAsync(out + SYNC_OFF, 0, SYNC_FLOATS*sizeof(float), stream);      // slots + tags
  cvt16_kernel<<<512,  256, 0, stream>>>(Wss,  (f16*)(out + WS16_OFF), H2_*H_);
  cvt16_kernel<<<1536, 256, 0, stream>>>(Wih2, (f16*)(out + W216_OFF), 3*H_*H2_);
  cvt16_kernel<<<768,  256, 0, stream>>>(Whh2, (f16*)(out + WH216_OFF), 3*H_*H_);
  cvt16_kernel<<<1024, 256, 0, stream>>>(Wh,   (f16*)(out + WH16F_OFF), H2_*H2_);
  cvt16_kernel<<<896,  256, 0, stream>>>(V1w,  (f16*)(out + V1HF_OFF), H_*CAT_);
  packWhh1_kernel<<<768, 256, 0, stream>>>(Whh1, (f16*)(out + WH116T_OFF));
  repack_kernel<<<dim3(S_, B_), 256, 0, stream>>>(enc, (f16*)(out + ENC16_OFF));
  gx1_kernel<<<dim3(16, 6), 256, 0, stream>>>(emb, Wih1, bih1, out);
  encproj_mfma<<<dim3(4, 7, B_), 256, 0, stream>>>((const f16*)(out + ENC16_OFF),
      (const f16*)(out + WH16F_OFF), battn, (f16*)(out + ENCP16_OFF));
  scan_kernel<<<128, 1024, SM_BYTES, stream>>>(xmask, ymask,
      bhh1, bih2, bhh2, Wc, Vat, inith, initc, out);
  head_kernel<<<dim3(T_, 8), 512, 0, stream>>>(emb, (const f16*)(out + V1HF_OFF),
      V1b, Wpw, Wpb, out, ws);
  gemm2_kernel<<<dim3(782, 4), 256, 0, stream>>>((const ushort_t*)(ws + WS_G1), V2w, V2b, out, ws + WS_ROWSUM);
  normscatter_kernel<<<1024, 256, 0, stream>>>(out, ws, xidx);
}

// Round 11
// 1852.327 us; speedup vs baseline: 1.3018x; 1.3018x over previous
//
#include <hip/hip_runtime.h>
#include <hip/hip_bf16.h>

typedef unsigned short ushort_t;
typedef unsigned int u32;
typedef _Float16 f16;
typedef __attribute__((ext_vector_type(8))) short short8;
typedef __attribute__((ext_vector_type(4))) float f32x4;
typedef __attribute__((ext_vector_type(8))) _Float16 f16x8;
typedef __attribute__((ext_vector_type(4))) unsigned int u32x4;

#define T_ 64
#define B_ 16
#define S_ 400
#define E_ 128
#define H_ 256
#define H2_ 512
#define DV_ 50000
#define VOC_ 50050
#define CAT_ 896
#define NCLUS 8
#define RSL 50

// ---- d_out float offsets
#define YP_SZ   ((size_t)T_*B_*VOC_)              // 51,251,200 floats
#define HS_OFF  (YP_SZ)
#define WW_OFF  (HS_OFF + (size_t)T_*B_*H_)
#define CV_OFF  (WW_OFF + (size_t)T_*B_*S_)
// scratch carved out of the y_pred region (all consumed before gemm2 overwrites it):
#define ENCP16_OFF ((size_t)0)         // f16[16][400][512]
#define ENC16_OFF  ((size_t)1638400)   // f16[16][400][512]
#define WS16_OFF   ((size_t)3276800)   // f16[512][256]
#define W216_OFF   ((size_t)3342336)   // f16[768][512]
#define CTXALL_OFF ((size_t)3538944)   // f32[1024][512]
#define GX1_OFF    ((size_t)4063232)   // f32[1024][768]
#define WH216_OFF  ((size_t)4947968)   // f16[768][256]
#define WH116T_OFF ((size_t)5046272)   // f16[8][768][32] col-panel pack of Whh1
// tag-stamped exchange slots (dead y_pred region):
#define SYNC_OFF   ((size_t)5144576)
#define S1STR      528                  // payload[0..511]=uctx, [512]=esum, tag@520
#define S1TAG      520
#define S2STR      816                  // payload[0..767]=gh1p, [768..799]=s2, tag@808
#define S2TAG      808
#define S2REG      ((size_t)16*NCLUS*S1STR)
#define SYNC_FLOATS ((size_t)16*NCLUS*(S1STR + S2STR))
#define WH16F_OFF  ((size_t)5316608)   // f16[512][512]  (Wh converted)
#define V1HF_OFF   ((size_t)5447680)   // f16[256][896]  (V1w converted)

// ---- ws float offsets
#define WS_ROWSUM 0      // f32[1024]
#define WS_GV     1024   // f32[1024]
#define WS_G1     2048   // bf16[1024][256]

__device__ __forceinline__ float fsig(float x){ return 1.f/(1.f+__expf(-x)); }
__device__ __forceinline__ float ftanh(float x){ float e=__expf(2.f*x); return 1.f - 2.f/(e+1.f); }

#define PADK(k) ((k) + (((k)>>5)<<2))

#define AT_ST(p, v)  __hip_atomic_store((p), (v), __ATOMIC_RELAXED, __HIP_MEMORY_SCOPE_AGENT)
#define AT_LD(p)     __hip_atomic_load((p), __ATOMIC_RELAXED, __HIP_MEMORY_SCOPE_AGENT)
#define AT_STI(p, v) __hip_atomic_store((int*)(p), (v), __ATOMIC_RELAXED, __HIP_MEMORY_SCOPE_AGENT)
#define AT_LDI(p)    __hip_atomic_load((const int*)(p), __ATOMIC_RELAXED, __HIP_MEMORY_SCOPE_AGENT)

// ---- dynamic smem byte offsets (scan)
#define SM_ENC    0
#define SM_ENCP   51200
#define SM_GH1    102400
#define SM_SWS    105472
#define SM_VP     107776
#define SM_WCP    110080
#define SM_UCTX   112384
#define SM_HID    114432
#define SM_S1     115456
#define SM_G2X    116480
#define SM_G2H    116864
#define SM_COV    117248
#define SM_EV     117504
#define SM_XM     117760
#define SM_YM     118016
#define SM_HIDH   118272
#define SM_S1H    118784
#define SM_CTXH   119296
#define SM_S2S    120320
#define SM_PART   120448
#define SM_B1     120512
#define SM_B2     123584
#define SM_B3     126656
#define SM_GX     129728
#define SM_BYTES  132800

// ---------------------------------------------------------------- small converts
__global__ __launch_bounds__(256)
void cvt16_kernel(const float* src, f16* dst, int n){
  int i = blockIdx.x*256 + threadIdx.x;
  if (i < n) dst[i] = (f16)src[i];
}

__global__ __launch_bounds__(256)
void repack_kernel(const float* enc, f16* enc16){
  int s = blockIdx.x, b = blockIdx.y;
  const float* src = enc + ((size_t)s*B_ + b)*H2_;
  f16* dst = enc16 + ((size_t)b*S_ + s)*H2_;
  for (int k = threadIdx.x; k < H2_; k += 256) dst[k] = (f16)src[k];
}

// Whh1 [768][256] -> panels [jj][768][32]
__global__ __launch_bounds__(256)
void packWhh1_kernel(const float* W, f16* dst){
  int r = blockIdx.x, c = threadIdx.x;
  int jq = c >> 5, cc = c & 31;
  dst[((size_t)jq*768 + r)*32 + cc] = (f16)W[(size_t)r*H_ + c];
}

// ---------------------------------------------------------------- gx1 = emb @ Wih1^T + bih1
__global__ __launch_bounds__(256)
void gx1_kernel(const float* emb, const float* Wih1, const float* bih1, float* dout){
  __shared__ float As[64][33];
  __shared__ float Bs[128][33];
  int m0 = blockIdx.x*64, n0 = blockIdx.y*128;
  int tx = threadIdx.x & 15, ty = threadIdx.x >> 4;
  float acc[4][8] = {};
  for (int kt = 0; kt < E_; kt += 32){
    for (int l = threadIdx.x; l < 64*32; l += 256){
      int m = l>>5, k = l&31; As[m][k] = emb[(size_t)(m0+m)*E_ + kt + k];
    }
    for (int l = threadIdx.x; l < 128*32; l += 256){
      int n = l>>5, k = l&31; Bs[n][k] = Wih1[(size_t)(n0+n)*E_ + kt + k];
    }
    __syncthreads();
    for (int k = 0; k < 32; ++k){
      float a[4], bv[8];
      #pragma unroll
      for (int i=0;i<4;++i) a[i] = As[ty+16*i][k];
      #pragma unroll
      for (int j=0;j<8;++j) bv[j] = Bs[tx+16*j][k];
      #pragma unroll
      for (int i=0;i<4;++i)
        #pragma unroll
        for (int j=0;j<8;++j) acc[i][j] += a[i]*bv[j];
    }
    __syncthreads();
  }
  #pragma unroll
  for (int i=0;i<4;++i)
    #pragma unroll
    for (int j=0;j<8;++j){
      int m = m0 + ty + 16*i, n = n0 + tx + 16*j;
      dout[GX1_OFF + (size_t)m*768 + n] = acc[i][j] + bih1[n];
    }
}

// ---------------------------------------------------------------- enc_proj via f16 MFMA -> encp16
__global__ __launch_bounds__(256)
void encproj_mfma(const f16* enc16, const f16* Wh16, const float* battn, f16* ep16){
  int nx = blockIdx.x, my = blockIdx.y, bz = blockIdx.z;
  int tid = threadIdx.x;
  int w = tid >> 6, lane = tid & 63;
  int c16 = lane & 15, kg = lane >> 4;
  int m0 = my*64, n0 = nx*128 + w*32;
  f32x4 acc[4][2] = {};
  int col0 = n0 + c16, col1 = n0 + 16 + c16;
  for (int ks = 0; ks < 16; ++ks){
    int k0 = ks*32 + kg*8;
    f16x8 b0 = *(const f16x8*)(Wh16 + (size_t)col0*H2_ + k0);
    f16x8 b1 = *(const f16x8*)(Wh16 + (size_t)col1*H2_ + k0);
    #pragma unroll
    for (int mf = 0; mf < 4; ++mf){
      int s = m0 + mf*16 + c16; if (s > S_-1) s = S_-1;
      f16x8 a = *(const f16x8*)(enc16 + ((size_t)bz*S_ + s)*H2_ + k0);
      acc[mf][0] = __builtin_amdgcn_mfma_f32_16x16x32_f16(a, b0, acc[mf][0], 0, 0, 0);
      acc[mf][1] = __builtin_amdgcn_mfma_f32_16x16x32_f16(a, b1, acc[mf][1], 0, 0, 0);
    }
  }
  #pragma unroll
  for (int mf = 0; mf < 4; ++mf)
    #pragma unroll
    for (int nf = 0; nf < 2; ++nf){
      int col = n0 + nf*16 + c16;
      float bb = battn[col];
      #pragma unroll
      for (int r = 0; r < 4; ++r){
        int s = m0 + mf*16 + kg*4 + r;
        if (s < S_) ep16[((size_t)bz*S_ + s)*H2_ + col] = (f16)(acc[mf][nf][r] + bb);
      }
    }
}

// ---------------------------------------------------------------- f16 GEMV (1024 threads, 128 octets)
template<int R, int K, bool PAD>
__device__ __forceinline__ void gemv_f16t(const f16* W, const f16* xh, float* out_l, int tid){
  int o = tid >> 3, l8 = tid & 7;
  constexpr int NI = K/64;
  const f16x8* x8 = (const f16x8*)xh;
  f16x8 xv[NI];
  #pragma unroll
  for (int i = 0; i < NI; ++i) xv[i] = x8[i*8 + l8];
  #pragma unroll
  for (int it = 0; it < R/128; ++it){
    int d = o + it*128;
    const f16x8* w8 = (const f16x8*)(W + (size_t)d*K);
    float acc = 0.f;
    #pragma unroll
    for (int i = 0; i < NI; ++i){
      f16x8 w = w8[i*8 + l8];
      #pragma unroll
      for (int e = 0; e < 8; ++e) acc += (float)w[e] * (float)xv[i][e];
    }
    acc += __shfl_xor(acc,1,8); acc += __shfl_xor(acc,2,8); acc += __shfl_xor(acc,4,8);
    if (l8 == 0) out_l[PAD ? PADK(d) : d] = acc;
  }
}

// spin until all 8 tags of this cluster's region equal `want`
__device__ __forceinline__ void spin_tags(const float* base, int stride, int tagoff, int want, int tid){
  if (tid < 64){
    bool mine = tid < NCLUS;
    const float* tp = base + (size_t)(mine ? tid : 0)*stride + tagoff;
    while (true){
      int v = mine ? AT_LDI(tp) : want;
      if (__all(v == want)) break;
      __builtin_amdgcn_s_sleep(1);
    }
  }
  __syncthreads();
}

// ---------------------------------------------------------------- persistent scan: 128 blocks (8 per b, same-XCD clusters)
// round-9 structure (best measured: 1368us, FETCH 43MB). Phase-merge attempts
// (r10) spilled at the 64-VGPR allocator target (FETCH 97MB) — keep phases
// wide (many waves, few loads/thread), never deepen per-thread state.
__global__ __launch_bounds__(1024)
void scan_kernel(const float* xm, const float* ym,
                 const float* bhh1, const float* bih2, const float* bhh2,
                 const float* Wc, const float* Vat,
                 const float* inith, const float* initc,
                 float* dout)
{
  extern __shared__ char smem[];
  f16*   enc_s  = (f16*)(smem + SM_ENC);
  f16*   encp_s = (f16*)(smem + SM_ENCP);
  float* gh1_l  = (float*)(smem + SM_GH1);
  float* sWs_p  = (float*)(smem + SM_SWS);
  float* Vp     = (float*)(smem + SM_VP);
  float* Wcp    = (float*)(smem + SM_WCP);
  float* uctx   = (float*)(smem + SM_UCTX);
  float* hid_l  = (float*)(smem + SM_HID);
  float* s1_l   = (float*)(smem + SM_S1);
  float* g2x_l  = (float*)(smem + SM_G2X);
  float* g2h_l  = (float*)(smem + SM_G2H);
  float* cov_l  = (float*)(smem + SM_COV);
  float* ev_l   = (float*)(smem + SM_EV);
  float* xm_l   = (float*)(smem + SM_XM);
  float* ym_l   = (float*)(smem + SM_YM);
  f16*   hidh   = (f16*)(smem + SM_HIDH);
  f16*   s1h    = (f16*)(smem + SM_S1H);
  f16*   ctxh   = (f16*)(smem + SM_CTXH);
  float* s2s    = (float*)(smem + SM_S2S);
  float* part_l = (float*)(smem + SM_PART);
  float* b1l    = (float*)(smem + SM_B1);
  float* b2l    = (float*)(smem + SM_B2);
  float* b3l    = (float*)(smem + SM_B3);
  float* gxbuf  = (float*)(smem + SM_GX);

  const f16* Ws16   = (const f16*)(dout + WS16_OFF);
  const f16* W216   = (const f16*)(dout + W216_OFF);
  const f16* Wh216  = (const f16*)(dout + WH216_OFF);
  const f16* Wh116T = (const f16*)(dout + WH116T_OFF);
  const float* gx1  = dout + GX1_OFF;

  int blk = blockIdx.x, tid = threadIdx.x;
  // same-XCD clusters: blk = jj*16 + b  ->  XCD(blk%8) == b%8 for all jj
  int b = blk & 15, jj = blk >> 4;
  int wv = tid >> 6, ln = tid & 63;

  float* sl1 = dout + SYNC_OFF + (size_t)b*NCLUS*S1STR;       // cluster region
  float* sl2 = dout + SYNC_OFF + S2REG + (size_t)b*NCLUS*S2STR;
  float* sl1my = sl1 + (size_t)jj*S1STR;
  float* sl2my = sl2 + (size_t)jj*S2STR;

  // ---- init: pin enc/encp slice in LDS, load state, seed slot2 with inith
  {
    const u32x4* encg  = (const u32x4*)(dout + ENC16_OFF)  + (size_t)b*25600 + jj*3200;
    const u32x4* encpg = (const u32x4*)(dout + ENCP16_OFF) + (size_t)b*25600 + jj*3200;
    u32x4* encs4  = (u32x4*)enc_s;
    u32x4* encps4 = (u32x4*)encp_s;
    for (int i = tid; i < 3200; i += 1024){ encs4[i] = encg[i]; encps4[i] = encpg[i]; }
  }
  if (tid < 32)  s2s[tid] = inith[b*H_ + jj*32 + tid];
  if (tid < 512){ Vp[PADK(tid)] = Vat[tid]; Wcp[PADK(tid)] = Wc[tid]; }
  if (tid < RSL){ int s = jj*RSL + tid; cov_l[tid] = initc[b*S_ + s]; xm_l[tid] = xm[(size_t)s*B_ + b]; }
  if (tid >= 512 && tid < 576) ym_l[tid-512] = ym[(tid-512)*B_ + b];
  if (tid < 768){ b1l[tid] = bhh1[tid]; b2l[tid] = bih2[tid]; b3l[tid] = bhh2[tid];
                  gxbuf[tid] = gx1[(size_t)b*768 + tid]; }
  __syncthreads();
  // A' seed: gh1 partial from inith slice
  if (tid < 768){
    const f16x8* p8 = (const f16x8*)(Wh116T + ((size_t)jj*768 + tid)*32);
    float acc = 0.f;
    #pragma unroll
    for (int c4 = 0; c4 < 4; ++c4){
      f16x8 w = p8[c4];
      #pragma unroll
      for (int e = 0; e < 8; ++e) acc += (float)w[e] * s2s[c4*8+e];
    }
    AT_ST(&sl2my[tid], acc);
  } else if (tid < 800){
    AT_ST(&sl2my[768 + (tid-768)], s2s[tid-768]);
  }
  __syncthreads();
  if (tid == 0) AT_STI(&sl2my[S2TAG], 1);

  for (int t = 0; t < T_; ++t){
    int row = t*B_ + b;
    int want = t + 1;
    // S2 spin: hidden + gh1 partials for this step available
    spin_tags(sl2, S2STR, S2TAG, want, tid);
    // R: gather gh1 (8-way sum) + hidden slices
    if (tid < 768){
      float a = 0.f;
      #pragma unroll
      for (int q = 0; q < NCLUS; ++q) a += AT_LD(&sl2[(size_t)q*S2STR + tid]);
      gh1_l[tid] = a;
    } else {
      int j = tid - 768;   // 0..255
      float h = AT_LD(&sl2[(size_t)(j>>5)*S2STR + 768 + (j&31)]);
      hid_l[j] = h; hidh[j] = (f16)h;
    }
    __syncthreads();
    // B: gates1 -> s1 (replicated; gx from LDS prefetch buffer)
    if (tid < 256){
      int j = tid;
      float r = fsig(gxbuf[j]      + gh1_l[j]      + b1l[j]);
      float z = fsig(gxbuf[256+j]  + gh1_l[256+j]  + b1l[256+j]);
      float n = ftanh(gxbuf[512+j] + r*(gh1_l[512+j] + b1l[512+j]));
      float h = hid_l[j];
      float ymv = ym_l[t];
      float s1 = ymv*((1.f-z)*n + z*h) + (1.f-ymv)*h;
      s1_l[j] = s1; s1h[j] = (f16)s1;
    }
    __syncthreads();
    // C: sWs = Ws @ s1 (replicated, padded)
    gemv_f16t<512,256,true>(Ws16, s1h, sWs_p, tid);
    __syncthreads();
    // D: scores over local 50 rows (encp in LDS)
    {
      int kp = PADK(ln*8);
      float4 sA = *(const float4*)&sWs_p[kp], sB = *(const float4*)&sWs_p[kp+4];
      float4 vA = *(const float4*)&Vp[kp],    vB = *(const float4*)&Vp[kp+4];
      float4 cA = *(const float4*)&Wcp[kp],   cB = *(const float4*)&Wcp[kp+4];
      const f16x8* eps = (const f16x8*)encp_s;
      #pragma unroll
      for (int i = 0; i < 4; ++i){
        int r = wv + 16*i;
        if (r < RSL){
          f16x8 eu = eps[r*64 + ln];
          float cv = cov_l[r];
          float sc = 0.f;
          sc += ftanh((float)eu[0] + sA.x + cv*cA.x)*vA.x;
          sc += ftanh((float)eu[1] + sA.y + cv*cA.y)*vA.y;
          sc += ftanh((float)eu[2] + sA.z + cv*cA.z)*vA.z;
          sc += ftanh((float)eu[3] + sA.w + cv*cA.w)*vA.w;
          sc += ftanh((float)eu[4] + sB.x + cv*cB.x)*vB.x;
          sc += ftanh((float)eu[5] + sB.y + cv*cB.y)*vB.y;
          sc += ftanh((float)eu[6] + sB.z + cv*cB.z)*vB.z;
          sc += ftanh((float)eu[7] + sB.w + cv*cB.w)*vB.w;
          sc += __shfl_xor(sc,1);  sc += __shfl_xor(sc,2);  sc += __shfl_xor(sc,4);
          sc += __shfl_xor(sc,8);  sc += __shfl_xor(sc,16); sc += __shfl_xor(sc,32);
          if (ln == 0){
            float xmv = xm_l[r];
            ev_l[r] = __expf((xmv == 0.f) ? -1e9f : xmv*sc);  // |score|<~25: safe w/o max-sub
          }
        }
      }
    }
    __syncthreads();
    // EF: local ctx partial + esum partial -> slot1
    if (tid < 512){
      float acc = 0.f;
      #pragma unroll 5
      for (int s = 0; s < RSL; ++s) acc += ev_l[s] * (float)enc_s[s*H2_ + tid];
      AT_ST(&sl1my[tid], acc);
    } else if (tid >= 960){
      int l = tid - 960;
      float v = (l < RSL) ? ev_l[l] : 0.f;
      v += __shfl_xor(v,1);  v += __shfl_xor(v,2);  v += __shfl_xor(v,4);
      v += __shfl_xor(v,8);  v += __shfl_xor(v,16); v += __shfl_xor(v,32);
      if (l == 0) AT_ST(&sl1my[512], v);
    }
    __syncthreads();   // drain payload stores
    if (tid == 0) AT_STI(&sl1my[S1TAG], want);
    // X1 (hidden before spin): gx1[t+1] prefetch issue + g2h slice = Wh216[jj-rows] @ s1
    float gxn = 0.f;
    if (tid < 768){
      int tn = (t+1 < T_) ? t+1 : t;
      gxn = gx1[(size_t)(tn*B_ + b)*768 + tid];
    }
    {
      int o = tid >> 3, l8 = tid & 7;
      if (o < 96){
        int g = o >> 5, m = o & 31, wrow = g*256 + jj*32 + m;
        const f16x8* w8 = (const f16x8*)(Wh216 + (size_t)wrow*H_);
        const f16x8* x8 = (const f16x8*)s1h;
        float acc = 0.f;
        #pragma unroll
        for (int i = 0; i < 4; ++i){
          f16x8 w = w8[i*8 + l8], x = x8[i*8 + l8];
          #pragma unroll
          for (int e = 0; e < 8; ++e) acc += (float)w[e] * (float)x[e];
        }
        acc += __shfl_xor(acc,1,8); acc += __shfl_xor(acc,2,8); acc += __shfl_xor(acc,4,8);
        if (l8 == 0) g2h_l[o] = acc;
      }
    }
    if (tid < 768) gxbuf[tid] = gxn;
    // S1 spin
    spin_tags(sl1, S1STR, S1TAG, want, tid);
    // G: gather ctx partials + esums
    if (tid < 512){
      float us = 0.f;
      #pragma unroll
      for (int q = 0; q < NCLUS; ++q) us += AT_LD(&sl1[(size_t)q*S1STR + tid]);
      uctx[tid] = us;
    } else if (tid < 512 + NCLUS){
      part_l[tid-512] = AT_LD(&sl1[(size_t)(tid-512)*S1STR + 512]);
    }
    __syncthreads();
    // G2: finalize ctx, waw/cov bookkeeping
    {
      float es = 0.f;
      #pragma unroll
      for (int q = 0; q < NCLUS; ++q) es += part_l[q];
      float inv = 1.f/es;
      if (tid < 512){
        float v = uctx[tid]*inv;
        ctxh[tid] = (f16)v;
        if (jj == 0) __builtin_nontemporal_store(v, &dout[CTXALL_OFF + (size_t)row*H2_ + tid]);
      } else if (tid >= 640 && tid < 640 + RSL){
        int r = tid - 640;
        float w_ = ev_l[r]*inv;
        size_t ro = (size_t)row*S_ + jj*RSL + r;
        __builtin_nontemporal_store(w_, &dout[WW_OFF + ro]);
        float co = cov_l[r];
        __builtin_nontemporal_store(co, &dout[CV_OFF + ro]);
        cov_l[r] = co + w_;
      }
    }
    __syncthreads();
    // H: g2x slice = W216[jj-rows] @ ctx
    {
      int o = tid >> 3, l8 = tid & 7;
      if (o < 96){
        int g = o >> 5, m = o & 31, wrow = g*256 + jj*32 + m;
        const f16x8* w8 = (const f16x8*)(W216 + (size_t)wrow*H2_);
        const f16x8* x8 = (const f16x8*)ctxh;
        float acc = 0.f;
        #pragma unroll
        for (int i = 0; i < 8; ++i){
          f16x8 w = w8[i*8 + l8], x = x8[i*8 + l8];
          #pragma unroll
          for (int e = 0; e < 8; ++e) acc += (float)w[e] * (float)x[e];
        }
        acc += __shfl_xor(acc,1,8); acc += __shfl_xor(acc,2,8); acc += __shfl_xor(acc,4,8);
        if (l8 == 0) g2x_l[o] = acc;
      }
    }
    __syncthreads();
    // I: gates2 slice -> s2s + slot2 tail + hs
    if (tid < 32){
      int i = tid, j = jj*32 + i;
      float r = fsig(g2x_l[i]     + b2l[j]     + g2h_l[i]    + b3l[j]);
      float z = fsig(g2x_l[32+i]  + b2l[256+j] + g2h_l[32+i] + b3l[256+j]);
      float n = ftanh(g2x_l[64+i] + b2l[512+j] + r*(g2h_l[64+i] + b3l[512+j]));
      float s1v = s1_l[j];
      float ymv = ym_l[t];
      float s2 = ymv*((1.f-z)*n + z*s1v) + (1.f-ymv)*s1v;
      s2s[i] = s2;
      AT_ST(&sl2my[768 + i], s2);
      __builtin_nontemporal_store(s2, &dout[HS_OFF + (size_t)row*H_ + j]);
    }
    __syncthreads();
    // A': gh1 partial for next step = Wh116T[jj] @ s2_slice (panel from L2)
    if (tid < 768){
      const f16x8* p8 = (const f16x8*)(Wh116T + ((size_t)jj*768 + tid)*32);
      float acc = 0.f;
      #pragma unroll
      for (int c4 = 0; c4 < 4; ++c4){
        f16x8 w = p8[c4];
        #pragma unroll
        for (int e = 0; e < 8; ++e) acc += (float)w[e] * s2s[c4*8+e];
      }
      AT_ST(&sl2my[tid], acc);
    }
    __syncthreads();   // drain payload stores
    if (tid == 0) AT_STI(&sl2my[S2TAG], t + 2);
  }
}

// ---------------------------------------------------------------- G1 = tanh([hs|ctx|emb]@V1^T+b) bf16, g = sigmoid(...Wp)
__global__ __launch_bounds__(512)
void head_kernel(const float* emb, const f16* V1H, const float* V1b,
                 const float* Wpw, const float* Wpb, float* dout, float* ws)
{
  __shared__ float hc[2][CAT_];
  int t = blockIdx.x, b0 = blockIdx.y*2, tid = threadIdx.x;
  for (int i = tid; i < 2*CAT_; i += 512){
    int bb = i / CAT_, k = i % CAT_;
    int b = b0 + bb;
    float v;
    if (k < H_)           v = dout[HS_OFF     + ((size_t)(t*B_+b))*H_  + k];
    else if (k < H_+H2_)  v = dout[CTXALL_OFF + ((size_t)(t*B_+b))*H2_ + (k-H_)];
    else                  v = emb[((size_t)(t*B_+b))*E_ + (k-H_-H2_)];
    hc[bb][k] = v;
  }
  __syncthreads();
  __hip_bfloat16* G1 = (__hip_bfloat16*)(ws + WS_G1);
  {
    int j = tid & 255, bb = tid >> 8;
    const f16x8* wv8 = (const f16x8*)(V1H + (size_t)j*CAT_);
    float acc = 0.f;
    #pragma unroll 4
    for (int kk = 0; kk < CAT_/8; ++kk){
      f16x8 w = wv8[kk];
      #pragma unroll
      for (int e = 0; e < 8; ++e) acc += hc[bb][kk*8+e]*(float)w[e];
    }
    G1[((size_t)(t*B_ + b0 + bb))*H_ + j] = __float2bfloat16(ftanh(acc + V1b[j]));
  }
  if (tid < 128){
    int bb = tid >> 6, l = tid & 63;
    float acc = 0.f;
    for (int k = l; k < CAT_; k += 64) acc += hc[bb][k]*Wpw[k];
    acc += __shfl_xor(acc,1);  acc += __shfl_xor(acc,2);  acc += __shfl_xor(acc,4);
    acc += __shfl_xor(acc,8);  acc += __shfl_xor(acc,16); acc += __shfl_xor(acc,32);
    if (l == 0) ws[WS_GV + t*B_ + b0 + bb] = fsig(acc + Wpb[0]);
  }
}

// ---------------------------------------------------------------- logits GEMM (bf16 MFMA, 256-row m-tile) + exp + rowsums
__global__ __launch_bounds__(256)
void gemm2_kernel(const ushort_t* G1, const float* V2w, const float* V2b,
                  float* dout, float* rowsum)
{
  __shared__ float rows_l[256];
  int tid = threadIdx.x;
  rows_l[tid] = 0.f;
  int m0 = blockIdx.y * 256;
  int n0 = blockIdx.x * 64;
  int lane = tid & 63, w = tid >> 6;
  int c16 = lane & 15, kg = lane >> 4;
  int col = n0 + w*16 + c16;
  int colc = col < DV_ ? col : DV_-1;
  bool valid = col < DV_;
  f32x4 acc[16] = {};
  const float* brow = V2w + (size_t)colc*H_;
  for (int ks = 0; ks < 8; ++ks){
    int k0 = ks*32 + kg*8;
    short8 bf;
    #pragma unroll
    for (int i = 0; i < 8; ++i){
      __hip_bfloat16 hb = __float2bfloat16(brow[k0+i]);
      union { __hip_bfloat16 h; short s; } u; u.h = hb;
      bf[i] = u.s;
    }
    #pragma unroll
    for (int mf = 0; mf < 16; ++mf){
      const short8* ap = (const short8*)(G1 + ((size_t)(m0 + mf*16 + c16))*H_ + k0);
      acc[mf] = __builtin_amdgcn_mfma_f32_16x16x32_bf16(*ap, bf, acc[mf], 0, 0, 0);
    }
  }
  float bias = valid ? V2b[colc] : 0.f;
  __syncthreads();
  #pragma unroll
  for (int mf = 0; mf < 16; ++mf){
    #pragma unroll
    for (int r = 0; r < 4; ++r){
      float v = valid ? __expf(acc[mf][r] + bias) : 0.f;
      int rloc = mf*16 + kg*4 + r;
      if (valid) __builtin_nontemporal_store(v, &dout[(size_t)(m0 + rloc)*VOC_ + col]);
      float s = v;
      s += __shfl_xor(s, 1, 16); s += __shfl_xor(s, 2, 16);
      s += __shfl_xor(s, 4, 16); s += __shfl_xor(s, 8, 16);
      if (c16 == 0) atomicAdd(&rows_l[rloc], s);
    }
  }
  __syncthreads();
  atomicAdd(&rowsum[m0 + tid], rows_l[tid]);
}

// ---------------------------------------------------------------- fused normalize + pointer scatter (+ EXT zero)
__global__ __launch_bounds__(256)
void normscatter_kernel(float* dout, const float* ws, const int* xidx){
  int row = blockIdx.x; int b = row & 15;
  float gv = ws[WS_GV + row];
  float sc = gv / ws[WS_ROWSUM + row];
  float g1 = 1.f - gv;
  float2* y2 = (float2*)(dout + (size_t)row * VOC_);
  for (int i = threadIdx.x; i < VOC_/2; i += 256){
    float2 v = y2[i];
    int e0 = 2*i;
    v.x = (e0   < DV_) ? v.x*sc : 0.f;
    v.y = (e0+1 < DV_) ? v.y*sc : 0.f;
    y2[i] = v;
  }
  __syncthreads();
  const float* ww = dout + WW_OFF + (size_t)row*S_;
  float* y = dout + (size_t)row*VOC_;
  for (int s = threadIdx.x; s < S_; s += 256){
    atomicAdd(&y[xidx[(size_t)s*B_ + b]], g1*ww[s]);
  }
}

extern "C" void kernel_launch(void* const* d_in, const int* in_sizes, int n_in,
                              void* d_out, int out_size, void* d_ws, size_t ws_size,
                              hipStream_t stream)
{
  (void)in_sizes; (void)n_in; (void)out_size; (void)ws_size;
  const float* emb   = (const float*)d_in[0];
  const float* enc   = (const float*)d_in[1];
  const float* inith = (const float*)d_in[2];
  const float* xmask = (const float*)d_in[3];
  const float* ymask = (const float*)d_in[4];
  const int*   xidx  = (const int*)d_in[5];
  const float* initc = (const float*)d_in[7];
  const float* Wh    = (const float*)d_in[8];
  const float* Wss   = (const float*)d_in[9];
  const float* Wc    = (const float*)d_in[10];
  const float* battn = (const float*)d_in[11];
  const float* Vat   = (const float*)d_in[12];
  const float* Wih1  = (const float*)d_in[13];
  const float* Whh1  = (const float*)d_in[14];
  const float* bih1  = (const float*)d_in[15];
  const float* bhh1  = (const float*)d_in[16];
  const float* Wih2  = (const float*)d_in[17];
  const float* Whh2  = (const float*)d_in[18];
  const float* bih2  = (const float*)d_in[19];
  const float* bhh2  = (const float*)d_in[20];
  const float* V1w   = (const float*)d_in[21];
  const float* V1b   = (const float*)d_in[22];
  const float* V2w   = (const float*)d_in[23];
  const float* V2b   = (const float*)d_in[24];
  const float* Wpw   = (const float*)d_in[25];
  const float* Wpb   = (const float*)d_in[26];
  float* out = (float*)d_out;
  float* ws  = (float*)d_ws;

  hipFuncSetAttribute(reinterpret_cast<const void*>(scan_kernel),
                      hipFuncAttributeMaxDynamicSharedMemorySize, SM_BYTES);

  hipMemsetAsync(d_ws, 0, 2048*sizeof(float), stream);                       // rowsum + gv
  hipMemsetAsync(out + SYNC_OFF, 0, SYNC_FLOATS*sizeof(float), stream);      // slots + tags
  cvt16_kernel<<<512,  256, 0, stream>>>(Wss,  (f16*)(out + WS16_OFF), H2_*H_);
  cvt16_kernel<<<1536, 256, 0, stream>>>(Wih2, (f16*)(out + W216_OFF), 3*H_*H2_);
  cvt16_kernel<<<768,  256, 0, stream>>>(Whh2, (f16*)(out + WH216_OFF), 3*H_*H_);
  cvt16_kernel<<<1024, 256, 0, stream>>>(Wh,   (f16*)(out + WH16F_OFF), H2_*H2_);
  cvt16_kernel<<<896,  256, 0, stream>>>(V1w,  (f16*)(out + V1HF_OFF), H_*CAT_);
  packWhh1_kernel<<<768, 256, 0, stream>>>(Whh1, (f16*)(out + WH116T_OFF));
  repack_kernel<<<dim3(S_, B_), 256, 0, stream>>>(enc, (f16*)(out + ENC16_OFF));
  gx1_kernel<<<dim3(16, 6), 256, 0, stream>>>(emb, Wih1, bih1, out);
  encproj_mfma<<<dim3(4, 7, B_), 256, 0, stream>>>((const f16*)(out + ENC16_OFF),
      (const f16*)(out + WH16F_OFF), battn, (f16*)(out + ENCP16_OFF));
  scan_kernel<<<128, 1024, SM_BYTES, stream>>>(xmask, ymask,
      bhh1, bih2, bhh2, Wc, Vat, inith, initc, out);
  head_kernel<<<dim3(T_, 8), 512, 0, stream>>>(emb, (const f16*)(out + V1HF_OFF),
      V1b, Wpw, Wpb, out, ws);
  gemm2_kernel<<<dim3(782, 4), 256, 0, stream>>>((const ushort_t*)(ws + WS_G1), V2w, V2b, out, ws + WS_ROWSUM);
  normscatter_kernel<<<1024, 256, 0, stream>>>(out, ws, xidx);
}